// Round 1
// baseline (258.668 us; speedup 1.0000x reference)
//
#include <hip/hip_runtime.h>

typedef __bf16 bf16;
typedef __bf16 bf16x4 __attribute__((ext_vector_type(4)));
typedef __bf16 bf16x8 __attribute__((ext_vector_type(8)));
typedef float f32x4 __attribute__((ext_vector_type(4)));
typedef unsigned int u32x4 __attribute__((ext_vector_type(4)));

#define MFMA16 __builtin_amdgcn_mfma_f32_16x16x32_bf16

// ---------------------------------------------------------------------------
// K0: convert the four 256x256 weight matrices f32 -> bf16 (layout unchanged,
// [O][C] row-major = A-operand ready, K-contiguous).
__global__ __launch_bounds__(256) void k_cvt_w(const float* __restrict__ w0, const float* __restrict__ w1,
                                               const float* __restrict__ w2, const float* __restrict__ w3,
                                               bf16* __restrict__ dst) {
    int t = blockIdx.x * 256 + threadIdx.x;  // 65536 threads, 4 elems each
    const float* srcs[4] = {w0, w1, w2, w3};
    int which = t >> 14;                      // uniform per block (64 blocks/matrix)
    int idx = (t & 16383) * 4;
    f32x4 v = *(const f32x4*)(srcs[which] + idx);
    bf16x4 o;
    o[0] = (bf16)v[0]; o[1] = (bf16)v[1]; o[2] = (bf16)v[2]; o[3] = (bf16)v[3];
    *(bf16x4*)(dst + (size_t)which * 65536 + idx) = o;
}

// ---------------------------------------------------------------------------
// K1: transpose+convert activations: src [B][256][N] f32 -> dst rows [n][256] bf16
// (c-contiguous = B^T operand for the projection GEMMs). 64x64 tile via LDS.
__global__ __launch_bounds__(256) void k_transp(const float* __restrict__ src, bf16* __restrict__ dst,
                                                int N, int dstBatchRows, int rowOff) {
    int b = blockIdx.z;
    int c0 = blockIdx.y * 64, n0 = blockIdx.x * 64;
    __shared__ float T[64][65];
    int t = threadIdx.x;
    const float* s = src + ((size_t)b * 256 + c0) * N + n0;
#pragma unroll
    for (int i = 0; i < 4; i++) {
        int flat = i * 256 + t;
        int row = flat >> 4;          // c 0..63
        int col = (flat & 15) * 4;    // n
        f32x4 v = *(const f32x4*)(s + (size_t)row * N + col);
        T[row][col + 0] = v[0]; T[row][col + 1] = v[1];
        T[row][col + 2] = v[2]; T[row][col + 3] = v[3];
    }
    __syncthreads();
#pragma unroll
    for (int i = 0; i < 4; i++) {
        int flat = i * 256 + t;
        int nrow = flat >> 4;         // n 0..63
        int c4 = (flat & 15) * 4;     // c
        bf16x4 o;
        o[0] = (bf16)T[c4 + 0][nrow]; o[1] = (bf16)T[c4 + 1][nrow];
        o[2] = (bf16)T[c4 + 2][nrow]; o[3] = (bf16)T[c4 + 3][nrow];
        *(bf16x4*)(dst + ((size_t)(b * dstBatchRows + rowOff + n0 + nrow)) * 256 + c0 + c4) = o;
    }
}

// ---------------------------------------------------------------------------
// K2: projection GEMM  D[o][n] = sum_c W[o][c] * Xt[n][c]  (+bias), bf16 MFMA.
// 64x64 tile / block (4 waves, wave = 16 M-rows x 64 N-cols), K staged 32/iter.
// MODE 0: store bf16 [b*8+head][n][32]   (Q and K for attention)
// MODE 1: store bf16 [b*8+head][32][Nk]  (V transposed for PV B-operand)
// MODE 2: store f32  [b][n][256]         (o-projection pre-LN)
template <int MODE>
__global__ __launch_bounds__(256) void k_proj(const bf16* __restrict__ A, const bf16* __restrict__ Bt,
                                              const float* __restrict__ bias, void* __restrict__ DstV,
                                              int Nrows) {
    int b = blockIdx.z, m0 = blockIdx.y * 64, n0 = blockIdx.x * 64;
    __shared__ bf16 As[64 * 40];  // +8 bf16 row pad
    __shared__ bf16 Bs[64 * 40];
    int t = threadIdx.x;
    int w = t >> 6, lane = t & 63;
    int lrow = lane & 15, lk = lane >> 4;
    f32x4 acc[4] = {};
    int r = t >> 2, cc = (t & 3) * 8;
    for (int kc = 0; kc < 256; kc += 32) {
        u32x4 va = *(const u32x4*)(A + (size_t)(m0 + r) * 256 + kc + cc);
        u32x4 vb = *(const u32x4*)(Bt + ((size_t)b * Nrows + n0 + r) * 256 + kc + cc);
        *(u32x4*)(As + r * 40 + cc) = va;
        *(u32x4*)(Bs + r * 40 + cc) = vb;
        __syncthreads();
        bf16x8 af = *(const bf16x8*)(As + (w * 16 + lrow) * 40 + lk * 8);
#pragma unroll
        for (int ct = 0; ct < 4; ct++) {
            bf16x8 bfr = *(const bf16x8*)(Bs + (ct * 16 + lrow) * 40 + lk * 8);
            acc[ct] = MFMA16(af, bfr, acc[ct], 0, 0, 0);
        }
        __syncthreads();
    }
    // C/D layout: col = lane&15, row = (lane>>4)*4 + reg  [verified m89/m91]
    int o0 = m0 + w * 16 + lk * 4;
    f32x4 b4 = *(const f32x4*)(bias + o0);
#pragma unroll
    for (int ct = 0; ct < 4; ct++) {
        int n = n0 + ct * 16 + lrow;
        if (MODE == 0) {
            bf16* Dst = (bf16*)DstV;
            int head = o0 >> 5, dd = o0 & 31;
            bf16x4 pv;
#pragma unroll
            for (int i = 0; i < 4; i++) pv[i] = (bf16)(acc[ct][i] + b4[i]);
            *(bf16x4*)(Dst + ((size_t)(b * 8 + head) * Nrows + n) * 32 + dd) = pv;
        } else if (MODE == 1) {
            bf16* Dst = (bf16*)DstV;
            int head = o0 >> 5, dd = o0 & 31;
            size_t base = ((size_t)(b * 8 + head) * 32 + dd) * (size_t)Nrows + n;
#pragma unroll
            for (int i = 0; i < 4; i++) Dst[base + (size_t)i * Nrows] = (bf16)(acc[ct][i] + b4[i]);
        } else {
            float* Dst = (float*)DstV;
            f32x4 v;
#pragma unroll
            for (int i = 0; i < 4; i++) v[i] = acc[ct][i] + b4[i];
            *(f32x4*)(Dst + ((size_t)b * Nrows + n) * 256 + o0) = v;
        }
    }
}

// ---------------------------------------------------------------------------
// K3: attention. Q [bh][4096][32], K [bh][3072][32], Vt [bh][32][3072], all bf16.
// Block = 4 waves, 64 q-rows; wave owns 16 q-rows. Softmax without max-shift
// (|logit*scale| <~ 0.7 by construction; shift-invariant => exact), so no
// online rescale: O_acc += exp(S)*V, l += rowsum(exp(S)), divide at end.
__global__ __launch_bounds__(256) void k_attn(const bf16* __restrict__ Q, const bf16* __restrict__ K,
                                              const bf16* __restrict__ Vt, bf16* __restrict__ aout) {
    int bh = blockIdx.y;
    int q0 = blockIdx.x * 64;
    int t = threadIdx.x, w = t >> 6, lane = t & 63;
    int lrow = lane & 15, lk = lane >> 4;
    __shared__ bf16 P[4][16 * 40];  // per-wave C/D->A round-trip buffer (no barriers needed)
    bf16* pw = &P[w][0];
    const bf16* kbase = K + (size_t)bh * 3072 * 32;
    const bf16* vbase = Vt + (size_t)bh * 32 * 3072;
    // A-operand (Q) lives in registers for the whole K loop:
    // A[m=lane&15][k=(lane>>4)*8+j], d=32 = exactly one MFMA K-step.
    bf16x8 aq = *(const bf16x8*)(Q + ((size_t)bh * 4096 + q0 + w * 16 + lrow) * 32 + lk * 8);
    f32x4 accO0 = {}, accO1 = {};
    float lsum[4] = {0.f, 0.f, 0.f, 0.f};
    const float scale = 0.17677669529663687f;  // 32^-0.5
    f32x4 zero = {};
    for (int kc = 0; kc < 3072; kc += 32) {
        bf16x8 bk0 = *(const bf16x8*)(kbase + (size_t)(kc + lrow) * 32 + lk * 8);
        bf16x8 bk1 = *(const bf16x8*)(kbase + (size_t)(kc + 16 + lrow) * 32 + lk * 8);
        f32x4 s0 = MFMA16(aq, bk0, zero, 0, 0, 0);
        f32x4 s1 = MFMA16(aq, bk1, zero, 0, 0, 0);
#pragma unroll
        for (int i = 0; i < 4; i++) {
            float p0 = __expf(s0[i] * scale);
            float p1 = __expf(s1[i] * scale);
            lsum[i] += p0 + p1;
            int row = lk * 4 + i;  // q-row within tile (C/D layout)
            pw[row * 40 + lrow] = (bf16)p0;
            pw[row * 40 + 16 + lrow] = (bf16)p1;
        }
        // read back as A-operand: P[m=q][k=kn], kn-contiguous
        bf16x8 ap = *(const bf16x8*)(pw + lrow * 40 + lk * 8);
        bf16x8 bv0 = *(const bf16x8*)(vbase + (size_t)lrow * 3072 + kc + lk * 8);
        bf16x8 bv1 = *(const bf16x8*)(vbase + (size_t)(16 + lrow) * 3072 + kc + lk * 8);
        accO0 = MFMA16(ap, bv0, accO0, 0, 0, 0);
        accO1 = MFMA16(ap, bv1, accO1, 0, 0, 0);
    }
    // row-sum reduction across the 16 lanes sharing lk (xor on lane bits 0..3)
#pragma unroll
    for (int off = 1; off < 16; off <<= 1) {
#pragma unroll
        for (int i = 0; i < 4; i++) lsum[i] += __shfl_xor(lsum[i], off, 64);
    }
    int b = bh >> 3, h = bh & 7;
#pragma unroll
    for (int i = 0; i < 4; i++) {
        float rl = 1.0f / lsum[i];
        int q = q0 + w * 16 + lk * 4 + i;
        size_t rowbase = ((size_t)b * 4096 + q) * 256 + h * 32;
        aout[rowbase + lrow] = (bf16)(accO0[i] * rl);
        aout[rowbase + 16 + lrow] = (bf16)(accO1[i] * rl);
    }
}

// ---------------------------------------------------------------------------
// K4: residual + LayerNorm(C) + transpose back to [b][c][n]. Tile 32n x 256c.
__global__ __launch_bounds__(256) void k_ln(const float* __restrict__ opre, const float* __restrict__ s3,
                                            const float* __restrict__ lnw, const float* __restrict__ lnb,
                                            float* __restrict__ out) {
    int b = blockIdx.y;
    int n0 = blockIdx.x * 32;
    __shared__ float T[32][257];
    __shared__ float mu_s[32], rs_s[32];
    int t = threadIdx.x;
    // phase A: opre tile [32n][256c], coalesced along c
#pragma unroll
    for (int i = 0; i < 8; i++) {
        int flat = i * 256 + t;
        int n = flat >> 6;
        int c = (flat & 63) * 4;
        f32x4 v = *(const f32x4*)(opre + ((size_t)b * 4096 + n0 + n) * 256 + c);
        T[n][c + 0] = v[0]; T[n][c + 1] = v[1]; T[n][c + 2] = v[2]; T[n][c + 3] = v[3];
    }
    __syncthreads();
    // phase B: add residual from s3 [b][c][n], coalesced along n
#pragma unroll
    for (int i = 0; i < 8; i++) {
        int flat = i * 256 + t;
        int c = flat >> 3;
        int n = (flat & 7) * 4;
        f32x4 v = *(const f32x4*)(s3 + ((size_t)b * 256 + c) * 4096 + n0 + n);
        T[n + 0][c] += v[0]; T[n + 1][c] += v[1]; T[n + 2][c] += v[2]; T[n + 3][c] += v[3];
    }
    __syncthreads();
    // phase C: per-row mean/var (wave w handles rows w*8..w*8+7)
    int w = t >> 6, lane = t & 63;
    for (int j = 0; j < 8; j++) {
        int row = w * 8 + j;
        float x0 = T[row][lane], x1 = T[row][lane + 64];
        float x2 = T[row][lane + 128], x3 = T[row][lane + 192];
        float s = x0 + x1 + x2 + x3;
        float s2 = x0 * x0 + x1 * x1 + x2 * x2 + x3 * x3;
#pragma unroll
        for (int off = 1; off < 64; off <<= 1) {
            s += __shfl_xor(s, off, 64);
            s2 += __shfl_xor(s2, off, 64);
        }
        if (lane == 0) {
            float mu = s * (1.0f / 256.0f);
            float var = s2 * (1.0f / 256.0f) - mu * mu;
            mu_s[row] = mu;
            rs_s[row] = rsqrtf(var + 1e-5f);
        }
    }
    __syncthreads();
    // phase D: write out[b][c][n0..n0+31], each thread owns one c-row
    int c = t;
    float wv = lnw[c], bv = lnb[c];
#pragma unroll
    for (int i = 0; i < 8; i++) {
        int n = i * 4;
        f32x4 o;
#pragma unroll
        for (int k = 0; k < 4; k++)
            o[k] = (T[n + k][c] - mu_s[n + k]) * rs_s[n + k] * wv + bv;
        *(f32x4*)(out + ((size_t)b * 256 + c) * 4096 + n0 + n) = o;
    }
}

// ---------------------------------------------------------------------------
extern "C" void kernel_launch(void* const* d_in, const int* in_sizes, int n_in,
                              void* d_out, int out_size, void* d_ws, size_t ws_size,
                              hipStream_t stream) {
    const float* s3  = (const float*)d_in[0];
    const float* s4  = (const float*)d_in[1];
    const float* s5  = (const float*)d_in[2];
    const float* qw  = (const float*)d_in[3];
    const float* qb  = (const float*)d_in[4];
    const float* kw  = (const float*)d_in[5];
    const float* kb  = (const float*)d_in[6];
    const float* vw  = (const float*)d_in[7];
    const float* vb  = (const float*)d_in[8];
    const float* ow  = (const float*)d_in[9];
    const float* ob  = (const float*)d_in[10];
    const float* lnw = (const float*)d_in[11];
    const float* lnb = (const float*)d_in[12];
    float* out = (float*)d_out;
    char* ws = (char*)d_ws;

    // workspace layout (peak 17.5 MB, with dead-buffer overlays):
    bf16* s3t  = (bf16*)(ws);                                  // [2][4096][256] 4 MB
    bf16* s45t = (bf16*)(ws + (4ull << 20));                   // [2][3072][256] 3 MB
    bf16* Wb   = (bf16*)(ws + (7ull << 20));                   // 4x[256][256]  512 KB
    bf16* Qb   = (bf16*)(ws + (7ull << 20) + (512ull << 10));  // [16][4096][32] 4 MB
    bf16* Kb   = Qb + (2ull * 8 * 4096 * 32);                  // [16][3072][32] 3 MB
    bf16* Vtb  = Kb + (2ull * 8 * 3072 * 32);                  // [16][32][3072] 3 MB
    bf16* aout = s3t;            // s3t dead after Q projection
    float* opre = (float*)Qb;    // Q/K/Vt dead after attention (8 MB)

    k_cvt_w<<<256, 256, 0, stream>>>(qw, kw, vw, ow, Wb);
    k_transp<<<dim3(64, 4, 2), 256, 0, stream>>>(s3, s3t, 4096, 4096, 0);
    k_transp<<<dim3(32, 4, 2), 256, 0, stream>>>(s4, s45t, 2048, 3072, 0);
    k_transp<<<dim3(16, 4, 2), 256, 0, stream>>>(s5, s45t, 1024, 3072, 2048);
    k_proj<0><<<dim3(64, 4, 2), 256, 0, stream>>>(Wb,          s3t,  qb, (void*)Qb,  4096);
    k_proj<0><<<dim3(48, 4, 2), 256, 0, stream>>>(Wb + 65536,  s45t, kb, (void*)Kb,  3072);
    k_proj<1><<<dim3(48, 4, 2), 256, 0, stream>>>(Wb + 131072, s45t, vb, (void*)Vtb, 3072);
    k_attn<<<dim3(64, 16), 256, 0, stream>>>(Qb, Kb, Vtb, aout);
    k_proj<2><<<dim3(64, 4, 2), 256, 0, stream>>>(Wb + 196608, aout, ob, (void*)opre, 4096);
    k_ln<<<dim3(128, 2), 256, 0, stream>>>(opre, s3, lnw, lnb, out);
}